// Round 12
// baseline (223.289 us; speedup 1.0000x reference)
//
#include <hip/hip_runtime.h>
#include <stdint.h>

// out[p,b,o] = sum_i x*w0 + (1-x)*w1 = sum_i x*(w0-w1) + sum_i w1
// R20: no-dup w stream at 1024B strips via EXPLICIT pair exchange.
// Measured DRAM law (R14/15/16): efficiency ~ min(1, strip/1024B); R16 is
// at the read wall but duplicates w 2x. Pair (bid, bid^128) = same 256-col
// tile; block h streams only k-half h (R16 loop verbatim) and publishes
// each step's d as 2-bit codes (lo=w0bit, hi=w1bit; 1 u32/thread/step,
// 64KB/block). Release-fence + flag; partner acquire-spins (deadlock-free:
// grid 256 = all blocks co-resident; publish happens before any wait).
// Pass 2 replays the partner's k-half from its code buffer (L3-hot):
// decode 2b -> bf16 into the SAME bds layout, same BRDMFMA. colsum(w1) of
// the partner half = popc of code hi-bits. w read from DRAM exactly once.
// Fallback: verbatim R16 if ws too small.

#define NP 16
#define NB 512
#define NI 2048
#define NO 2048
#define JW 64               // u32 words per i-row in xp
#define OT 256              // o-columns per tile
#define KS 32               // k-rows per step
#define NST1 32             // steps per k-half
#define CBW 16384           // code u32 per block (32 steps x 512 thr)
#define XP_WORDS (NP * NB * JW)   // 524288 u32 = 2 MiB

typedef __attribute__((ext_vector_type(8))) short short8;
typedef __attribute__((ext_vector_type(4))) float f32x4;

__global__ __launch_bounds__(256) void pack_x_kernel(const float* __restrict__ x,
                                                     uint32_t* __restrict__ xp) {
    const int gtid = blockIdx.x * 256 + threadIdx.x;
    const int row  = gtid >> 6;     // p*NB + b
    const int lane = gtid & 63;
    const float* src = x + (size_t)row * NI;
    unsigned long long* dst = (unsigned long long*)(xp + (size_t)row * JW);
#pragma unroll 4
    for (int k = 0; k < NI / 64; ++k) {
        const float v = src[k * 64 + lane];
        const unsigned long long m = __ballot(v != 0.0f);
        if (lane == 0) dst[k] = m;
    }
}

// bf16 truncation (exact for d in {-1,0,1} and w1 in {0,1})
#define BF16(f) ((uint32_t)(__float_as_uint(f) >> 16))

// issue next step's w: k-rows 4wv..4wv+3, lane cols 4l..4l+3, both mats
#define WISS(s0_, s1_) do {                                                    \
    _Pragma("unroll")                                                          \
    for (int _j = 0; _j < 4; ++_j) {                                           \
        s0_[_j] = *(const f32x4*)(w0n + (size_t)_j * NO);                      \
        s1_[_j] = *(const f32x4*)(w1n + (size_t)_j * NO);                      \
    }                                                                          \
    w0n += (size_t)KS * NO; w1n += (size_t)KS * NO;                            \
} while (0)

// convert a w set -> bf16 d tile rows 4wv..+3 of bds[b_]; colsum(w1).  (R16)
#define CVT(s0_, s1_, b_) do {                                                 \
    _Pragma("unroll")                                                          \
    for (int _c = 0; _c < 4; ++_c) {                                           \
        const float _d0 = s0_[0][_c] - s1_[0][_c];                             \
        const float _d1 = s0_[1][_c] - s1_[1][_c];                             \
        const float _d2 = s0_[2][_c] - s1_[2][_c];                             \
        const float _d3 = s0_[3][_c] - s1_[3][_c];                             \
        cs[_c] += s1_[0][_c] + s1_[1][_c] + s1_[2][_c] + s1_[3][_c];           \
        uint2 _st;                                                             \
        _st.x = BF16(_d0) | (BF16(_d1) << 16);                                 \
        _st.y = BF16(_d2) | (BF16(_d3) << 16);                                 \
        *(uint2*)&bds[b_][4 * lane + _c][4 * wv] = _st;                        \
    }                                                                          \
} while (0)

// CVT + pack 16 codes (bit 2*(4c+j): lo=w0bit, hi=w1bit) + publish store
#define CVTP(s0_, s1_, b_) do {                                                \
    uint32_t _cw = 0;                                                          \
    _Pragma("unroll")                                                          \
    for (int _c = 0; _c < 4; ++_c) {                                           \
        const float _d0 = s0_[0][_c] - s1_[0][_c];                             \
        const float _d1 = s0_[1][_c] - s1_[1][_c];                             \
        const float _d2 = s0_[2][_c] - s1_[2][_c];                             \
        const float _d3 = s0_[3][_c] - s1_[3][_c];                             \
        cs[_c] += s1_[0][_c] + s1_[1][_c] + s1_[2][_c] + s1_[3][_c];           \
        uint2 _st;                                                             \
        _st.x = BF16(_d0) | (BF16(_d1) << 16);                                 \
        _st.y = BF16(_d2) | (BF16(_d3) << 16);                                 \
        *(uint2*)&bds[b_][4 * lane + _c][4 * wv] = _st;                        \
        _Pragma("unroll")                                                      \
        for (int _j = 0; _j < 4; ++_j)                                         \
            _cw |= (((__float_as_uint(s0_[_j][_c]) >> 23) & 1u)                \
                  | ((__float_as_uint(s1_[_j][_c]) >> 22) & 2u))               \
                   << (2 * (4 * _c + _j));                                     \
    }                                                                          \
    cbp[0] = _cw; cbp += 512;                                                  \
} while (0)

// decode one code word -> bf16 d tile rows 4wv..+3 of bds[b_]; colsum from hi bits
#define DEC1(cx) ((((cx) & 3u) == 1u) ? 0x3F80u                                \
                  : ((((cx) & 3u) == 2u) ? 0xBF80u : 0u))
#define DECODE(cw_, b_) do {                                                   \
    _Pragma("unroll")                                                          \
    for (int _c = 0; _c < 4; ++_c) {                                           \
        uint2 _st;                                                             \
        _st.x = DEC1((cw_) >> (8 * _c))     | (DEC1((cw_) >> (8 * _c + 2)) << 16); \
        _st.y = DEC1((cw_) >> (8 * _c + 4)) | (DEC1((cw_) >> (8 * _c + 6)) << 16); \
        cs[_c] += (float)__popc((cw_) & (0xAAu << (8 * _c)));                  \
        *(uint2*)&bds[b_][4 * lane + _c][4 * wv] = _st;                        \
    }                                                                          \
} while (0)

// issue next x words (2 m-frag rows' step-word) and bump
#define XISS(xw) do {                                                          \
    xw[0] = xn[0]; xw[1] = xn[1024];                                           \
    xn += 1;                                                                   \
} while (0)

// expand A-frags from packed-x words: bit -> bf16 {0,1}  (R14-verified)
#define AEXP(afr, xw) do {                                                     \
    _Pragma("unroll")                                                          \
    for (int _mi = 0; _mi < 2; ++_mi) {                                        \
        const uint32_t _by = (xw[_mi] >> klo8) & 0xFFu;                        \
        union { uint32_t u[4]; short8 s; } _cv;                                \
        _cv.u[0] = (_by & 1u   ? 0x3F80u : 0u) | (_by & 2u   ? 0x3F800000u : 0u); \
        _cv.u[1] = (_by & 4u   ? 0x3F80u : 0u) | (_by & 8u   ? 0x3F800000u : 0u); \
        _cv.u[2] = (_by & 16u  ? 0x3F80u : 0u) | (_by & 32u  ? 0x3F800000u : 0u); \
        _cv.u[3] = (_by & 64u  ? 0x3F80u : 0u) | (_by & 128u ? 0x3F800000u : 0u); \
        afr[_mi] = _cv.s;                                                      \
    }                                                                          \
} while (0)

// read B-frags from bds[b_] (two b64s each; pitch 88B) + 2m x 16n MFMA
#define BRDMFMA(afr, b_) do {                                                  \
    _Pragma("unroll")                                                          \
    for (int _nj = 0; _nj < 16; ++_nj) {                                       \
        union { uint2 q[2]; short8 s; } _u;                                    \
        _u.q[0] = *(const uint2*)&bds[b_][_nj * 16 + lanelo][klo8];            \
        _u.q[1] = *(const uint2*)&bds[b_][_nj * 16 + lanelo][klo8 + 4];        \
        _Pragma("unroll")                                                      \
        for (int _mi = 0; _mi < 2; ++_mi)                                      \
            acc[_mi][_nj] = __builtin_amdgcn_mfma_f32_16x16x32_bf16(           \
                afr[_mi], _u.s, acc[_mi][_nj], 0, 0, 0);                       \
    }                                                                          \
} while (0)

// lgkmcnt-only barrier: LDS visibility without draining the w vmcnt FIFO
#define BARLDS() asm volatile("s_waitcnt lgkmcnt(0)\n\ts_barrier" ::: "memory")

// ------------------------------------------------------------ new kernel ----
__global__ __launch_bounds__(512, 2) void evo_xch(const float* __restrict__ w,
                                                  const uint32_t* __restrict__ xp,
                                                  uint32_t* __restrict__ cb,
                                                  uint32_t* __restrict__ flg,
                                                  float* __restrict__ out) {
    __shared__ __align__(16) uint16_t bds[2][OT][44];  // 44 KB, dbuf d tile
    __shared__ float csl[8][64][4];                    // 8 KB, colsum partials

    const int tid    = threadIdx.x;
    const int lane   = tid & 63;
    const int wv     = __builtin_amdgcn_readfirstlane(tid >> 6);  // 0..7
    const int lanelo = lane & 15;
    const int klo8   = (lane >> 4) * 8;
    const int bid    = blockIdx.x;
    const int h      = bid >> 7;          // row-half owned; k-half streamed
    const int t      = bid & 127;
    const int p      = t >> 3;            // 0..15
    const int og     = t & 7;             // 0..7

    const size_t wq = (size_t)NI * NO;
    const float* w0n = w + (size_t)p * wq + (size_t)(h * 1024 + 4 * wv) * NO
                     + og * OT + 4 * lane;
    const float* w1n = w0n + (size_t)NP * wq;
    const uint32_t* xn = xp + ((size_t)p * NB + h * 256 + wv * 32 + lanelo) * JW
                       + h * 32;                       // own k-half words
    uint32_t* cbp = cb + (size_t)bid * CBW + tid;      // own publish cursor

    f32x4 acc[2][16];
#pragma unroll
    for (int mi = 0; mi < 2; ++mi)
#pragma unroll
        for (int nj = 0; nj < 16; ++nj) acc[mi][nj] = (f32x4)0.0f;
    float cs[4] = {0.0f, 0.0f, 0.0f, 0.0f};

    f32x4 wA0[4], wA1[4], wB0[4], wB1[4];
    uint32_t xwA[2], xwB[2];

    // ---- pass 1: own k-half, R16 structure + code publish (32 steps) ----
    WISS(wA0, wA1);               // w(0)
    WISS(wB0, wB1);               // w(1)
    XISS(xwA); XISS(xwB);         // x(0), x(1)
    CVTP(wA0, wA1, 0);            // step 0 -> buf0 + publish
    WISS(wA0, wA1);               // w(2)
    BARLDS();

#pragma unroll 1
    for (int ss = 0; ss < 16; ++ss) {
        {   // even step s = 2ss : buf0, xwA
            short8 afr[2];
            AEXP(afr, xwA);
            if (ss < 15) XISS(xwA);            // x(2ss+2)
            BRDMFMA(afr, 0);
            CVTP(wB0, wB1, 1);                 // step 2ss+1 -> buf1
            if (ss < 15) WISS(wB0, wB1);       // w(2ss+3)
            BARLDS();
        }
        {   // odd step s = 2ss+1 : buf1, xwB
            short8 afr[2];
            AEXP(afr, xwB);
            if (ss < 15) XISS(xwB);            // x(2ss+3)
            BRDMFMA(afr, 1);
            if (ss < 15) {
                CVTP(wA0, wA1, 0);             // step 2ss+2 -> buf0
                if (ss < 14) WISS(wA0, wA1);   // w(2ss+4), last valid = w(31)
                BARLDS();
            }
        }
    }

    // ---- publish / handshake (deadlock-free: publish precedes any wait) ----
    __syncthreads();                           // drains vmcnt: all code stores done
    if (tid == 0) {
        __threadfence();                       // agent fence: L2 writeback
        __hip_atomic_store(flg + bid, 1u, __ATOMIC_RELEASE,
                           __HIP_MEMORY_SCOPE_AGENT);
        uint32_t v;
        do {
            v = __hip_atomic_load(flg + (bid ^ 128), __ATOMIC_ACQUIRE,
                                  __HIP_MEMORY_SCOPE_AGENT);
            if (!v) __builtin_amdgcn_s_sleep(8);
        } while (!v);
    }
    __syncthreads();
    if (lane == 0) {                           // per-wave acquire (cache inv)
        uint32_t v = __hip_atomic_load(flg + (bid ^ 128), __ATOMIC_ACQUIRE,
                                       __HIP_MEMORY_SCOPE_AGENT);
        asm volatile("" :: "v"(v));
    }
    BARLDS();

    // ---- pass 2: partner k-half from its code buffer (32 steps) ----
    xn = xp + ((size_t)p * NB + h * 256 + wv * 32 + lanelo) * JW + (1 - h) * 32;
    const uint32_t* cb2 = cb + (size_t)(bid ^ 128) * CBW + tid;

    uint32_t cwA = cb2[0];
    uint32_t cwB = cb2[512];
    XISS(xwA); XISS(xwB);         // x(0), x(1) of partner half
    DECODE(cwA, 0);               // step 0 -> buf0
    cwA = cb2[2 * 512];
    BARLDS();

#pragma unroll 1
    for (int tt = 0; tt < 16; ++tt) {
        {   // even step s = 2tt : buf0, xwA
            short8 afr[2];
            AEXP(afr, xwA);
            if (tt < 15) XISS(xwA);
            BRDMFMA(afr, 0);
            DECODE(cwB, 1);                    // step 2tt+1 -> buf1
            if (tt < 15) cwB = cb2[(size_t)(2 * tt + 3) * 512];
            BARLDS();
        }
        {   // odd step s = 2tt+1 : buf1, xwB
            short8 afr[2];
            AEXP(afr, xwB);
            if (tt < 15) XISS(xwB);
            BRDMFMA(afr, 1);
            if (tt < 15) {
                DECODE(cwA, 0);                // step 2tt+2 -> buf0
                if (tt < 14) cwA = cb2[(size_t)(2 * tt + 4) * 512];
                BARLDS();
            }
        }
    }

    // ---- colsum reduce + epilogue (exact: integers <= 2048) ----
    csl[wv][lane][0] = cs[0]; csl[wv][lane][1] = cs[1];
    csl[wv][lane][2] = cs[2]; csl[wv][lane][3] = cs[3];
    __syncthreads();

    float* obase = out + ((size_t)p * NB + h * 256 + wv * 32) * NO + og * OT;
#pragma unroll
    for (int nj = 0; nj < 16; ++nj) {
        const int colT = nj * 16 + lanelo;
        float csT = 0.0f;
#pragma unroll
        for (int q = 0; q < 8; ++q) csT += csl[q][colT >> 2][colT & 3];
#pragma unroll
        for (int mi = 0; mi < 2; ++mi) {
            const int r0 = mi * 16 + (lane >> 4) * 4;
            const f32x4 v = acc[mi][nj];
            obase[(size_t)(r0 + 0) * NO + colT] = v[0] + csT;
            obase[(size_t)(r0 + 1) * NO + colT] = v[1] + csT;
            obase[(size_t)(r0 + 2) * NO + colT] = v[2] + csT;
            obase[(size_t)(r0 + 3) * NO + colT] = v[3] + csT;
        }
    }
}

// ----------------------------------------------- fallback: R16 verbatim ----
__global__ __launch_bounds__(512, 2) void evo_w4(const float* __restrict__ w,
                                                 const uint32_t* __restrict__ xp,
                                                 float* __restrict__ out) {
    __shared__ __align__(16) uint16_t bds[2][OT][44];
    __shared__ float csl[8][64][4];

    const int tid    = threadIdx.x;
    const int lane   = tid & 63;
    const int wv     = __builtin_amdgcn_readfirstlane(tid >> 6);
    const int lanelo = lane & 15;
    const int klo8   = (lane >> 4) * 8;
    const int h      = blockIdx.x >> 7;
    const int t      = blockIdx.x & 127;
    const int p      = t >> 3;
    const int og     = t & 7;

    const size_t wq = (size_t)NI * NO;
    const float* w0n = w + (size_t)p * wq + (size_t)(4 * wv) * NO
                     + og * OT + 4 * lane;
    const float* w1n = w0n + (size_t)NP * wq;
    const uint32_t* xn = xp + ((size_t)p * NB + h * 256 + wv * 32 + lanelo) * JW;

    f32x4 acc[2][16];
#pragma unroll
    for (int mi = 0; mi < 2; ++mi)
#pragma unroll
        for (int nj = 0; nj < 16; ++nj) acc[mi][nj] = (f32x4)0.0f;
    float cs[4] = {0.0f, 0.0f, 0.0f, 0.0f};

    f32x4 wA0[4], wA1[4], wB0[4], wB1[4];
    uint32_t xwA[2], xwB[2];

    WISS(wA0, wA1);
    WISS(wB0, wB1);
    XISS(xwA); XISS(xwB);
    CVT(wA0, wA1, 0);
    WISS(wA0, wA1);
    BARLDS();

#pragma unroll 1
    for (int ss = 0; ss < 32; ++ss) {
        {
            short8 afr[2];
            AEXP(afr, xwA);
            if (ss < 31) XISS(xwA);
            BRDMFMA(afr, 0);
            CVT(wB0, wB1, 1);
            if (ss < 31) WISS(wB0, wB1);
            BARLDS();
        }
        {
            short8 afr[2];
            AEXP(afr, xwB);
            if (ss < 31) XISS(xwB);
            BRDMFMA(afr, 1);
            if (ss < 31) {
                CVT(wA0, wA1, 0);
                if (ss < 30) WISS(wA0, wA1);
                BARLDS();
            }
        }
    }

    csl[wv][lane][0] = cs[0]; csl[wv][lane][1] = cs[1];
    csl[wv][lane][2] = cs[2]; csl[wv][lane][3] = cs[3];
    __syncthreads();

    float* obase = out + ((size_t)p * NB + h * 256 + wv * 32) * NO + og * OT;
#pragma unroll
    for (int nj = 0; nj < 16; ++nj) {
        const int colT = nj * 16 + lanelo;
        float csT = 0.0f;
#pragma unroll
        for (int q = 0; q < 8; ++q) csT += csl[q][colT >> 2][colT & 3];
#pragma unroll
        for (int mi = 0; mi < 2; ++mi) {
            const int r0 = mi * 16 + (lane >> 4) * 4;
            const f32x4 v = acc[mi][nj];
            obase[(size_t)(r0 + 0) * NO + colT] = v[0] + csT;
            obase[(size_t)(r0 + 1) * NO + colT] = v[1] + csT;
            obase[(size_t)(r0 + 2) * NO + colT] = v[2] + csT;
            obase[(size_t)(r0 + 3) * NO + colT] = v[3] + csT;
        }
    }
}

// ---------------------------------------------------------------- launch ----
extern "C" void kernel_launch(void* const* d_in, const int* in_sizes, int n_in,
                              void* d_out, int out_size, void* d_ws, size_t ws_size,
                              hipStream_t stream) {
    const float* x = (const float*)d_in[0];   // (16,512,2048) fp32 {0,1}
    const float* w = (const float*)d_in[1];   // (2,16,1,2048,2048) fp32 {0,1}
    float* out     = (float*)d_out;           // (16,512,2048) fp32
    uint32_t* xp   = (uint32_t*)d_ws;         // 2 MiB packed x
    uint32_t* cb   = xp + XP_WORDS;           // 16 MiB code exchange
    uint32_t* flg  = cb + (size_t)256 * CBW;  // 256 flags

    pack_x_kernel<<<dim3((NP * NB * 64) / 256), dim3(256), 0, stream>>>(x, xp);

    const size_t need = ((size_t)XP_WORDS + (size_t)256 * CBW + 256) * 4;
    if (ws_size >= need) {
        hipMemsetAsync(flg, 0, 256 * sizeof(uint32_t), stream);
        evo_xch<<<dim3(256), dim3(512), 0, stream>>>(w, xp, cb, flg, out);
    } else {
        evo_w4<<<dim3(256), dim3(512), 0, stream>>>(w, xp, out);
    }
}